// Round 1
// baseline (276.303 us; speedup 1.0000x reference)
//
#include <hip/hip_runtime.h>
#include <hip/hip_bf16.h>

typedef __attribute__((ext_vector_type(4))) float f32x4;
typedef __attribute__((ext_vector_type(8))) short bf16x8;

#define MFMA(a, b, c) __builtin_amdgcn_mfma_f32_16x16x32_bf16(a, b, c, 0, 0, 0)

__device__ __forceinline__ short f2bf(float f) {
    union { float f; unsigned u; } v; v.f = f;
    unsigned r = v.u + 0x7fffu + ((v.u >> 16) & 1u);
    return (short)(r >> 16);
}

__device__ __forceinline__ bf16x8 cvt8(f32x4 a, f32x4 b) {
    bf16x8 r;
    r[0] = f2bf(a[0]); r[1] = f2bf(a[1]); r[2] = f2bf(a[2]); r[3] = f2bf(a[3]);
    r[4] = f2bf(b[0]); r[5] = f2bf(b[1]); r[6] = f2bf(b[2]); r[7] = f2bf(b[3]);
    return r;
}

// Prep: convert 5 weight mats to bf16 (wq[64][1024], wk=[lk1;lv1][128][1024],
// wv=[lk2;lv2][128][1024]) and build W_eff[1024][64] = sum_h lh_w[:, h*64+d].
__global__ __launch_bounds__(256) void prep_kernel(
        const float* __restrict__ lq_w, const float* __restrict__ lk1_w,
        const float* __restrict__ lk2_w, const float* __restrict__ lv1_w,
        const float* __restrict__ lv2_w, const float* __restrict__ lh_w,
        short* __restrict__ wq, short* __restrict__ wk,
        short* __restrict__ wv, short* __restrict__ weff) {
    int t = blockIdx.x * 256 + threadIdx.x;
    if (blockIdx.x < 256) {           // t in [0, 65536): one element of each 64x1024 mat
        wq[t]          = f2bf(lq_w[t]);
        wk[t]          = f2bf(lk1_w[t]);
        wk[65536 + t]  = f2bf(lv1_w[t]);
        wv[t]          = f2bf(lk2_w[t]);
        wv[65536 + t]  = f2bf(lv2_w[t]);
    } else {                          // W_eff: i = j*64 + d
        int i = t - 65536;
        int j = i >> 6, d = i & 63;
        float s = 0.f;
        #pragma unroll
        for (int h = 0; h < 16; ++h) s += lh_w[j * 1024 + h * 64 + d];
        weff[i] = f2bf(s);
    }
}

// Fused main: each wave owns 16 rows. Phase 1: q/k1/v1/k2/v2 via MFMA (K=1024).
// Gate in-register (shfl reduce). Head -> private LDS patch -> phase 2 GEMM vs W_eff.
__global__ __launch_bounds__(256, 2) void gating_main(
        const float* __restrict__ Q, const float* __restrict__ K,
        const float* __restrict__ V,
        const float* __restrict__ lq_b, const float* __restrict__ lk1_b,
        const float* __restrict__ lk2_b, const float* __restrict__ lv1_b,
        const float* __restrict__ lv2_b, const float* __restrict__ lh_b,
        const short* __restrict__ wq, const short* __restrict__ wk,
        const short* __restrict__ wv, const short* __restrict__ weff,
        float* __restrict__ out) {
    __shared__ __align__(16) short head_lds[4][16][72];  // +8 pad: 144B row stride
    const int wid  = threadIdx.x >> 6;
    const int lane = threadIdx.x & 63;
    const int lrow = lane & 15;   // A-row / B-col / C-col within 16-tile
    const int lkg  = lane >> 4;   // k-group (8 elems each) / C-row group
    const int rb   = blockIdx.x * 64 + wid * 16;

    f32x4 accq[4], acck[8], accv[8];
    const f32x4 z4 = {0.f, 0.f, 0.f, 0.f};
    #pragma unroll
    for (int i = 0; i < 4; ++i) accq[i] = z4;
    #pragma unroll
    for (int i = 0; i < 8; ++i) { acck[i] = z4; accv[i] = z4; }

    const float* qp = Q + (size_t)(rb + lrow) * 1024 + lkg * 8;
    const float* kp = K + (size_t)(rb + lrow) * 1024 + lkg * 8;
    const float* vp = V + (size_t)(rb + lrow) * 1024 + lkg * 8;
    const short* wqp = wq + lrow * 1024 + lkg * 8;
    const short* wkp = wk + lrow * 1024 + lkg * 8;
    const short* wvp = wv + lrow * 1024 + lkg * 8;

    #pragma unroll 1
    for (int kc = 0; kc < 32; ++kc) {
        const int kb = kc * 32;
        // A fragments: 8 contiguous f32 per lane from Q/K/V rows
        f32x4 q0 = *(const f32x4*)(qp + kb);
        f32x4 q1 = *(const f32x4*)(qp + kb + 4);
        f32x4 k0 = *(const f32x4*)(kp + kb);
        f32x4 k1v = *(const f32x4*)(kp + kb + 4);
        f32x4 v0 = *(const f32x4*)(vp + kb);
        f32x4 v1v = *(const f32x4*)(vp + kb + 4);
        // B fragments straight from bf16 weights (lane = out-col, 16B contiguous k)
        bf16x8 bq[4], bk[8], bv[8];
        #pragma unroll
        for (int nf = 0; nf < 4; ++nf)
            bq[nf] = *(const bf16x8*)(wqp + nf * 16384 + kb);
        #pragma unroll
        for (int nf = 0; nf < 8; ++nf) {
            bk[nf] = *(const bf16x8*)(wkp + nf * 16384 + kb);
            bv[nf] = *(const bf16x8*)(wvp + nf * 16384 + kb);
        }
        bf16x8 aq = cvt8(q0, q1);
        bf16x8 ak = cvt8(k0, k1v);
        bf16x8 av = cvt8(v0, v1v);
        #pragma unroll
        for (int nf = 0; nf < 4; ++nf) accq[nf] = MFMA(aq, bq[nf], accq[nf]);
        #pragma unroll
        for (int nf = 0; nf < 8; ++nf) acck[nf] = MFMA(ak, bk[nf], acck[nf]);
        #pragma unroll
        for (int nf = 0; nf < 8; ++nf) accv[nf] = MFMA(av, bv[nf], accv[nf]);
    }

    // Biases (per output column; all 4 acc regs share the column)
    #pragma unroll
    for (int nf = 0; nf < 4; ++nf) {
        const float bq_ = lq_b[nf * 16 + lrow];
        const float bk1 = lk1_b[nf * 16 + lrow];
        const float bv1 = lv1_b[nf * 16 + lrow];
        const float bk2 = lk2_b[nf * 16 + lrow];
        const float bv2 = lv2_b[nf * 16 + lrow];
        #pragma unroll
        for (int i = 0; i < 4; ++i) {
            accq[nf][i]     += bq_;
            acck[nf][i]     += bk1;
            acck[4 + nf][i] += bv1;
            accv[nf][i]     += bk2;
            accv[4 + nf][i] += bv2;
        }
    }

    // Gates: kv1 = q.k1, kv2 = q.k2 per row (row = lkg*4 + i); reduce over the
    // 16 lanes of this k-group (xor masks < 16 stay in-group). Then head -> LDS (bf16).
    #pragma unroll
    for (int i = 0; i < 4; ++i) {
        float p1 = 0.f, p2 = 0.f;
        #pragma unroll
        for (int nf = 0; nf < 4; ++nf) {
            p1 += accq[nf][i] * acck[nf][i];
            p2 += accq[nf][i] * accv[nf][i];
        }
        #pragma unroll
        for (int m = 1; m < 16; m <<= 1) {
            p1 += __shfl_xor(p1, m, 64);
            p2 += __shfl_xor(p2, m, 64);
        }
        const float mx = fmaxf(p1, p2);
        const float e1 = __expf(p1 - mx);
        const float e2 = __expf(p2 - mx);
        const float inv = 1.f / (e1 + e2);
        const float g1 = e1 * inv, g2 = e2 * inv;
        #pragma unroll
        for (int nf = 0; nf < 4; ++nf) {
            const float h = g1 * acck[4 + nf][i] + g2 * accv[4 + nf][i];
            head_lds[wid][lkg * 4 + i][nf * 16 + lrow] = f2bf(h);
        }
    }
    asm volatile("s_waitcnt lgkmcnt(0)" ::: "memory");  // wave-private LDS: no barrier needed

    // Phase 2: out[16 x 1024] = head[16 x 64] @ W_eff^T + lh_b
    const bf16x8 ha0 = *(const bf16x8*)&head_lds[wid][lrow][lkg * 8];
    const bf16x8 ha1 = *(const bf16x8*)&head_lds[wid][lrow][32 + lkg * 8];

    const size_t orow = (size_t)(rb + lkg * 4) * 1024;
    #pragma unroll 1
    for (int jt = 0; jt < 16; ++jt) {
        const int jb = jt * 64;
        #pragma unroll
        for (int nf = 0; nf < 4; ++nf) {
            const int col = jb + nf * 16 + lrow;
            const float bb = lh_b[col];
            f32x4 acc = {bb, bb, bb, bb};
            const short* wp = weff + col * 64 + lkg * 8;
            const bf16x8 w0 = *(const bf16x8*)(wp);
            const bf16x8 w1 = *(const bf16x8*)(wp + 32);
            acc = MFMA(ha0, w0, acc);
            acc = MFMA(ha1, w1, acc);
            #pragma unroll
            for (int i = 0; i < 4; ++i)
                out[orow + (size_t)i * 1024 + col] = acc[i];
        }
    }
}

extern "C" void kernel_launch(void* const* d_in, const int* in_sizes, int n_in,
                              void* d_out, int out_size, void* d_ws, size_t ws_size,
                              hipStream_t stream) {
    const float* Q     = (const float*)d_in[0];
    const float* K     = (const float*)d_in[1];
    const float* V     = (const float*)d_in[2];
    const float* lq_w  = (const float*)d_in[3];
    const float* lq_b  = (const float*)d_in[4];
    const float* lk1_w = (const float*)d_in[5];
    const float* lk1_b = (const float*)d_in[6];
    const float* lk2_w = (const float*)d_in[7];
    const float* lk2_b = (const float*)d_in[8];
    const float* lv1_w = (const float*)d_in[9];
    const float* lv1_b = (const float*)d_in[10];
    const float* lv2_w = (const float*)d_in[11];
    const float* lv2_b = (const float*)d_in[12];
    const float* lh_w  = (const float*)d_in[13];
    const float* lh_b  = (const float*)d_in[14];
    float* out = (float*)d_out;

    short* wq   = (short*)d_ws;          // 64*1024 bf16
    short* wk   = wq + 64 * 1024;        // 128*1024 (lk1; lv1)
    short* wv   = wk + 128 * 1024;       // 128*1024 (lk2; lv2)
    short* weff = wv + 128 * 1024;       // 1024*64

    prep_kernel<<<512, 256, 0, stream>>>(lq_w, lk1_w, lk2_w, lv1_w, lv2_w, lh_w,
                                         wq, wk, wv, weff);
    gating_main<<<512, 256, 0, stream>>>(Q, K, V, lq_b, lk1_b, lk2_b, lv1_b, lv2_b,
                                         lh_b, wq, wk, wv, weff, out);
}

// Round 2
// 272.661 us; speedup vs baseline: 1.0134x; 1.0134x over previous
//
#include <hip/hip_runtime.h>
#include <hip/hip_bf16.h>

typedef __attribute__((ext_vector_type(4))) float f32x4;
typedef __attribute__((ext_vector_type(8))) short bf16x8;
typedef __attribute__((ext_vector_type(4))) short bf16x4;

#define MFMA(a, b, c) __builtin_amdgcn_mfma_f32_16x16x32_bf16(a, b, c, 0, 0, 0)

__device__ __forceinline__ short f2bf(float f) {
    union { float f; unsigned u; } v; v.f = f;
    unsigned r = v.u + 0x7fffu + ((v.u >> 16) & 1u);
    return (short)(r >> 16);
}

__device__ __forceinline__ bf16x8 cvt8(f32x4 a, f32x4 b) {
    bf16x8 r;
    r[0] = f2bf(a[0]); r[1] = f2bf(a[1]); r[2] = f2bf(a[2]); r[3] = f2bf(a[3]);
    r[4] = f2bf(b[0]); r[5] = f2bf(b[1]); r[6] = f2bf(b[2]); r[7] = f2bf(b[3]);
    return r;
}

// ws layout:
//   W_all [320][1024] bf16  @ short offset 0        (rows: 0-63 q, 64-127 k1, 128-191 v1, 192-255 k2, 256-319 v2)
//   weff  [1024][64]  bf16  @ short offset 327680   (weff[j][d] = sum_h lh_w[j][h*64+d])
//   b_all [320]       f32   @ byte  offset 786432
//   head  [32768][64] bf16  @ byte  offset 787712
#define WS_WEFF   327680
#define WS_BALL_B 786432
#define WS_HEAD_B 787712

__global__ __launch_bounds__(256) void prep_kernel(
        const float* __restrict__ lq_w, const float* __restrict__ lk1_w,
        const float* __restrict__ lk2_w, const float* __restrict__ lv1_w,
        const float* __restrict__ lv2_w, const float* __restrict__ lh_w,
        const float* __restrict__ lq_b, const float* __restrict__ lk1_b,
        const float* __restrict__ lk2_b, const float* __restrict__ lv1_b,
        const float* __restrict__ lv2_b,
        short* __restrict__ W_all, short* __restrict__ weff,
        float* __restrict__ b_all) {
    int t = blockIdx.x * 256 + threadIdx.x;
    if (t < 327680) {                       // W_all
        int row = t >> 10, col = t & 1023;
        int seg = row >> 6, sr = row & 63;
        const float* src = (seg == 0) ? lq_w : (seg == 1) ? lk1_w
                         : (seg == 2) ? lv1_w : (seg == 3) ? lk2_w : lv2_w;
        W_all[t] = f2bf(src[sr * 1024 + col]);
    } else if (t < 393216) {                // weff
        int i = t - 327680;
        int j = i >> 6, d = i & 63;
        float s = 0.f;
        #pragma unroll
        for (int h = 0; h < 16; ++h) s += lh_w[j * 1024 + h * 64 + d];
        weff[i] = f2bf(s);
    } else if (t < 393536) {                // b_all
        int i = t - 393216;
        int seg = i >> 6, si = i & 63;
        const float* src = (seg == 0) ? lq_b : (seg == 1) ? lk1_b
                         : (seg == 2) ? lv1_b : (seg == 3) ? lk2_b : lv2_b;
        b_all[i] = src[si];
    }
}

// swizzled byte offset within one input's 4KB LDS chunk: [16 rows][128 bf16]
__device__ __forceinline__ int swz(int row, int kbf) {
    return (row * 256 + kbf * 2) ^ ((row & 7) << 4);
}

// Kernel 1: per block = 16 rows, full K=1024 in 8 chunks of 128.
// 4 waves; wave w owns col-tiles T = w + 4j (j=0..4 -> segment j).
// Q/K/V staged to LDS (bf16, swizzled, double-buffered) by all 256 threads.
__global__ __launch_bounds__(256) void gemm1_kernel(
        const float* __restrict__ Q, const float* __restrict__ K,
        const float* __restrict__ V, const short* __restrict__ W_all,
        const float* __restrict__ b_all, short* __restrict__ head) {
    __shared__ __align__(16) char lds[2][3][4096];
    const int tid  = threadIdx.x;
    const int wid  = tid >> 6;
    const int lane = tid & 63;
    const int lrow = lane & 15;
    const int lkg  = lane >> 4;
    const int RB   = blockIdx.x * 16;

    // staging coords: thread t stages row (t>>4), k-slot (t&15) of each input
    const int srow  = tid >> 4;
    const int kslot = tid & 15;
    const size_t gbase = (size_t)(RB + srow) * 1024 + kslot * 8;
    const int wb = swz(srow, kslot * 8);

    const float* __restrict__ Qp = Q + gbase;
    const float* __restrict__ Kp = K + gbase;
    const float* __restrict__ Vp = V + gbase;

    f32x4 acc[5];
    const f32x4 z4 = {0.f, 0.f, 0.f, 0.f};
    #pragma unroll
    for (int j = 0; j < 5; ++j) acc[j] = z4;

    // weight base pointers per j-tile (segment j, tile row base 16*(wid+4j))
    const short* wp0 = W_all + (16 * (wid +  0) + lrow) * 1024 + lkg * 8;
    const short* wp1 = W_all + (16 * (wid +  4) + lrow) * 1024 + lkg * 8;
    const short* wp2 = W_all + (16 * (wid +  8) + lrow) * 1024 + lkg * 8;
    const short* wp3 = W_all + (16 * (wid + 12) + lrow) * 1024 + lkg * 8;
    const short* wp4 = W_all + (16 * (wid + 16) + lrow) * 1024 + lkg * 8;

    // prologue: stage chunk 0
    {
        f32x4 a0 = *(const f32x4*)(Qp);
        f32x4 a1 = *(const f32x4*)(Qp + 4);
        f32x4 b0 = *(const f32x4*)(Kp);
        f32x4 b1 = *(const f32x4*)(Kp + 4);
        f32x4 c0 = *(const f32x4*)(Vp);
        f32x4 c1 = *(const f32x4*)(Vp + 4);
        *(bf16x8*)(&lds[0][0][wb]) = cvt8(a0, a1);
        *(bf16x8*)(&lds[0][1][wb]) = cvt8(b0, b1);
        *(bf16x8*)(&lds[0][2][wb]) = cvt8(c0, c1);
    }
    __syncthreads();

    #pragma unroll 1
    for (int c = 0; c < 8; ++c) {
        const int cur = c & 1;
        // prefetch next chunk (bulk-issued; hides HBM latency under MFMA)
        f32x4 a0, a1, b0, b1, c0, c1;
        if (c < 7) {
            const int go = (c + 1) * 128;
            a0 = *(const f32x4*)(Qp + go);
            a1 = *(const f32x4*)(Qp + go + 4);
            b0 = *(const f32x4*)(Kp + go);
            b1 = *(const f32x4*)(Kp + go + 4);
            c0 = *(const f32x4*)(Vp + go);
            c1 = *(const f32x4*)(Vp + go + 4);
        }
        const int co = c * 128;
        #pragma unroll
        for (int s = 0; s < 4; ++s) {
            const int rb = swz(lrow, s * 32 + lkg * 8);
            const bf16x8 AQ = *(const bf16x8*)(&lds[cur][0][rb]);
            const bf16x8 AK = *(const bf16x8*)(&lds[cur][1][rb]);
            const bf16x8 AV = *(const bf16x8*)(&lds[cur][2][rb]);
            const int o = co + s * 32;
            acc[0] = MFMA(AQ, *(const bf16x8*)(wp0 + o), acc[0]);
            acc[1] = MFMA(AK, *(const bf16x8*)(wp1 + o), acc[1]);
            acc[2] = MFMA(AK, *(const bf16x8*)(wp2 + o), acc[2]);
            acc[3] = MFMA(AV, *(const bf16x8*)(wp3 + o), acc[3]);
            acc[4] = MFMA(AV, *(const bf16x8*)(wp4 + o), acc[4]);
        }
        if (c < 7) {
            *(bf16x8*)(&lds[cur ^ 1][0][wb]) = cvt8(a0, a1);
            *(bf16x8*)(&lds[cur ^ 1][1][wb]) = cvt8(b0, b1);
            *(bf16x8*)(&lds[cur ^ 1][2][wb]) = cvt8(c0, c1);
        }
        __syncthreads();
    }

    // biases
    #pragma unroll
    for (int j = 0; j < 5; ++j) {
        const float bb = b_all[16 * (wid + 4 * j) + lrow];
        #pragma unroll
        for (int i = 0; i < 4; ++i) acc[j][i] += bb;
    }

    // dump acc to LDS as f32 [16][324] (reuses staging LDS; loop's final
    // __syncthreads already fenced the last reads)
    float* epi = (float*)lds;
    #pragma unroll
    for (int j = 0; j < 5; ++j) {
        const int colj = 16 * (wid + 4 * j) + lrow;
        #pragma unroll
        for (int i = 0; i < 4; ++i)
            epi[(lkg * 4 + i) * 324 + colj] = acc[j][i];
    }
    __syncthreads();

    // gates: row r = lrow; partial p = lkg over 16 q-dims each
    const int r = lrow;
    float p1 = 0.f, p2 = 0.f;
    #pragma unroll
    for (int jj = 0; jj < 16; ++jj) {
        const float qv = epi[r * 324 + lkg * 16 + jj];
        p1 += qv * epi[r * 324 +  64 + lkg * 16 + jj];
        p2 += qv * epi[r * 324 + 192 + lkg * 16 + jj];
    }
    p1 += __shfl_xor(p1, 16, 64); p1 += __shfl_xor(p1, 32, 64);
    p2 += __shfl_xor(p2, 16, 64); p2 += __shfl_xor(p2, 32, 64);
    const float mx = fmaxf(p1, p2);
    const float e1 = __expf(p1 - mx);
    const float e2 = __expf(p2 - mx);
    const float inv = 1.f / (e1 + e2);
    const float g1 = e1 * inv, g2 = e2 * inv;

    // head cols for this wave: [wid*16, wid*16+16); lane covers 4 cols
    const int cb = wid * 16 + lkg * 4;
    bf16x4 hv;
    #pragma unroll
    for (int j = 0; j < 4; ++j) {
        const float h = g1 * epi[r * 324 + 128 + cb + j]
                      + g2 * epi[r * 324 + 256 + cb + j];
        hv[j] = f2bf(h);
    }
    *(bf16x4*)(head + (size_t)(RB + r) * 64 + cb) = hv;
}

// Kernel 2: out[N][1024] = head[N][64] @ weff^T + lh_b.
// Wave-tile 16 rows x 64 cols; 32768 wave-tasks -> full occupancy.
__global__ __launch_bounds__(256) void gemm2_kernel(
        const short* __restrict__ head, const short* __restrict__ weff,
        const float* __restrict__ lh_b, float* __restrict__ out) {
    const int wid  = threadIdx.x >> 6;
    const int lane = threadIdx.x & 63;
    const int lrow = lane & 15;
    const int lkg  = lane >> 4;
    const int rt = blockIdx.x >> 2;
    const int cg = blockIdx.x & 3;
    const int RB = rt * 16;
    const int cbase = cg * 256 + wid * 64;

    const bf16x8 a0 = *(const bf16x8*)(head + (size_t)(RB + lrow) * 64 + lkg * 8);
    const bf16x8 a1 = *(const bf16x8*)(head + (size_t)(RB + lrow) * 64 + 32 + lkg * 8);

    #pragma unroll
    for (int nf = 0; nf < 4; ++nf) {
        const int col = cbase + nf * 16 + lrow;
        const float bb = lh_b[col];
        f32x4 acc = {bb, bb, bb, bb};
        const short* wp = weff + col * 64 + lkg * 8;
        acc = MFMA(a0, *(const bf16x8*)(wp), acc);
        acc = MFMA(a1, *(const bf16x8*)(wp + 32), acc);
        #pragma unroll
        for (int i = 0; i < 4; ++i)
            out[(size_t)(RB + lkg * 4 + i) * 1024 + col] = acc[i];
    }
}

extern "C" void kernel_launch(void* const* d_in, const int* in_sizes, int n_in,
                              void* d_out, int out_size, void* d_ws, size_t ws_size,
                              hipStream_t stream) {
    const float* Q     = (const float*)d_in[0];
    const float* K     = (const float*)d_in[1];
    const float* V     = (const float*)d_in[2];
    const float* lq_w  = (const float*)d_in[3];
    const float* lq_b  = (const float*)d_in[4];
    const float* lk1_w = (const float*)d_in[5];
    const float* lk1_b = (const float*)d_in[6];
    const float* lk2_w = (const float*)d_in[7];
    const float* lk2_b = (const float*)d_in[8];
    const float* lv1_w = (const float*)d_in[9];
    const float* lv1_b = (const float*)d_in[10];
    const float* lv2_w = (const float*)d_in[11];
    const float* lv2_b = (const float*)d_in[12];
    const float* lh_w  = (const float*)d_in[13];
    const float* lh_b  = (const float*)d_in[14];
    float* out = (float*)d_out;

    short* W_all = (short*)d_ws;
    short* weff  = W_all + WS_WEFF;
    float* b_all = (float*)((char*)d_ws + WS_BALL_B);
    short* head  = (short*)((char*)d_ws + WS_HEAD_B);

    prep_kernel<<<1538, 256, 0, stream>>>(lq_w, lk1_w, lk2_w, lv1_w, lv2_w, lh_w,
                                          lq_b, lk1_b, lk2_b, lv1_b, lv2_b,
                                          W_all, weff, b_all);
    gemm1_kernel<<<2048, 256, 0, stream>>>(Q, K, V, W_all, b_all, head);
    gemm2_kernel<<<8192, 256, 0, stream>>>(head, weff, lh_b, out);
}

// Round 3
// 227.697 us; speedup vs baseline: 1.2135x; 1.1975x over previous
//
#include <hip/hip_runtime.h>
#include <hip/hip_bf16.h>

typedef __attribute__((ext_vector_type(4))) float f32x4;
typedef __attribute__((ext_vector_type(8))) short bf16x8;

#define MFMA(a, b, c) __builtin_amdgcn_mfma_f32_16x16x32_bf16(a, b, c, 0, 0, 0)

__device__ __forceinline__ short f2bf(float f) {
    union { float f; unsigned u; } v; v.f = f;
    unsigned r = v.u + 0x7fffu + ((v.u >> 16) & 1u);
    return (short)(r >> 16);
}

__device__ __forceinline__ short f2bf_h(float f) {
    __hip_bfloat16 h = __float2bfloat16(f);
    return *reinterpret_cast<const short*>(&h);
}

__device__ __forceinline__ bf16x8 cvt8h(f32x4 a, f32x4 b) {
    bf16x8 r;
    #pragma unroll
    for (int i = 0; i < 4; ++i) {
        r[i]     = f2bf_h(a[i]);
        r[4 + i] = f2bf_h(b[i]);
    }
    return r;
}

__device__ __forceinline__ void gll16(const float* g, void* l) {
    __builtin_amdgcn_global_load_lds(
        (const __attribute__((address_space(1))) void*)g,
        (__attribute__((address_space(3))) void*)l, 16, 0, 0);
}

// ws layout:
//   W_all [320][1024] bf16 @ short 0      (rows: 0-63 q, 64-127 k1, 128-191 v1, 192-255 k2, 256-319 v2)
//   weff  [1024][64]  bf16 @ short 327680 (weff[j][d] = sum_h lh_w[j][h*64+d])
//   b_all [320]       f32  @ byte 786432
#define WS_WEFF   327680
#define WS_BALL_B 786432

__global__ __launch_bounds__(256) void prep_kernel(
        const float* __restrict__ lq_w, const float* __restrict__ lk1_w,
        const float* __restrict__ lk2_w, const float* __restrict__ lv1_w,
        const float* __restrict__ lv2_w, const float* __restrict__ lh_w,
        const float* __restrict__ lq_b, const float* __restrict__ lk1_b,
        const float* __restrict__ lk2_b, const float* __restrict__ lv1_b,
        const float* __restrict__ lv2_b,
        short* __restrict__ W_all, short* __restrict__ weff,
        float* __restrict__ b_all) {
    int t = blockIdx.x * 256 + threadIdx.x;
    if (t < 327680) {                       // W_all
        int row = t >> 10, col = t & 1023;
        int seg = row >> 6, sr = row & 63;
        const float* src = (seg == 0) ? lq_w : (seg == 1) ? lk1_w
                         : (seg == 2) ? lv1_w : (seg == 3) ? lk2_w : lv2_w;
        W_all[t] = f2bf(src[sr * 1024 + col]);
    } else if (t < 393216) {                // weff
        int i = t - 327680;
        int j = i >> 6, d = i & 63;
        float s = 0.f;
        #pragma unroll
        for (int h = 0; h < 16; ++h) s += lh_w[j * 1024 + h * 64 + d];
        weff[i] = f2bf(s);
    } else if (t < 393536) {                // b_all
        int i = t - 393216;
        int seg = i >> 6, si = i & 63;
        const float* src = (seg == 0) ? lq_b : (seg == 1) ? lk1_b
                         : (seg == 2) ? lv1_b : (seg == 3) ? lk2_b : lv2_b;
        b_all[i] = src[si];
    }
}

// Fused kernel: block = 16 rows, 4 waves.
// Phase 1: 5 projections (K=1024, 8 chunks of 128), Q/K/V staged f32 -> LDS via
// global_load_lds (source-granule XOR swizzle), weights direct from L2.
// Gate epilogue in LDS, head -> 2.3KB LDS patch, phase 2 GEMM vs W_eff.
__global__ __launch_bounds__(256, 3) void fused_kernel(
        const float* __restrict__ Q, const float* __restrict__ K,
        const float* __restrict__ V, const short* __restrict__ W_all,
        const float* __restrict__ b_all, const short* __restrict__ weff,
        const float* __restrict__ lh_b, float* __restrict__ out) {
    __shared__ __align__(16) float stage[2][3][16][128];   // 48 KB
    const int tid  = threadIdx.x;
    const int wid  = tid >> 6;
    const int lane = tid & 63;
    const int lrow = lane & 15;
    const int lkg  = lane >> 4;
    const int RB   = blockIdx.x * 16;

    const float* __restrict__ Qb = Q + (size_t)RB * 1024;
    const float* __restrict__ Kb = K + (size_t)RB * 1024;
    const float* __restrict__ Vb = V + (size_t)RB * 1024;

    const int srow_lo = lane >> 5;       // row within 2-row gll region
    const int jcol    = (lane & 31) * 4; // f32 index within row

    f32x4 acc[5];
    #pragma unroll
    for (int j = 0; j < 5; ++j) acc[j] = (f32x4){0.f, 0.f, 0.f, 0.f};

    // wave's weight base: tile j lives at + j*65536 shorts (16 rows per tile)
    const short* wbase = W_all + (size_t)(wid * 16 + lrow) * 1024 + lkg * 8;

    // prologue: stage chunk 0
    #pragma unroll
    for (int i = 0; i < 6; ++i) {
        const int inp = i >> 1;
        const int sub = (i & 1) * 4 + wid;
        const int row = sub * 2 + srow_lo;
        const int gk  = jcol ^ ((row & 7) << 2);
        const float* src = (inp == 0 ? Qb : inp == 1 ? Kb : Vb)
                         + (size_t)row * 1024 + gk;
        gll16(src, &stage[0][inp][sub * 2][0]);
    }
    __syncthreads();

    #pragma unroll 1
    for (int c = 0; c < 8; ++c) {
        const int cur = c & 1;
        // 1) weight fragments for this chunk — issued FIRST (L2, consumed soon;
        //    FIFO vmcnt => MFMAs don't wait on the HBM gll below)
        bf16x8 wf[4][5];
        #pragma unroll
        for (int s = 0; s < 4; ++s)
            #pragma unroll
            for (int j = 0; j < 5; ++j)
                wf[s][j] = *(const bf16x8*)(wbase + j * 65536 + c * 128 + s * 32);
        // 2) next-chunk staging (HBM; drained only at the barrier)
        if (c < 7) {
            #pragma unroll
            for (int i = 0; i < 6; ++i) {
                const int inp = i >> 1;
                const int sub = (i & 1) * 4 + wid;
                const int row = sub * 2 + srow_lo;
                const int gk  = (c + 1) * 128 + (jcol ^ ((row & 7) << 2));
                const float* src = (inp == 0 ? Qb : inp == 1 ? Kb : Vb)
                                 + (size_t)row * 1024 + gk;
                gll16(src, &stage[cur ^ 1][inp][sub * 2][0]);
            }
        }
        __builtin_amdgcn_sched_barrier(0);   // pin all issues above this point
        // 3) MFMA over 4 k-subtiles of buf[cur]
        const char* sbase = (const char*)&stage[cur][0][lrow][0];
        const int r7 = lrow & 7;
        #pragma unroll
        for (int s = 0; s < 4; ++s) {
            const int g0  = s * 8 + lkg * 2;
            const int a0o = ((g0)     ^ r7) << 4;
            const int a1o = ((g0 + 1) ^ r7) << 4;
            f32x4 q0 = *(const f32x4*)(sbase + a0o);
            f32x4 q1 = *(const f32x4*)(sbase + a1o);
            f32x4 k0 = *(const f32x4*)(sbase + 8192 + a0o);
            f32x4 k1 = *(const f32x4*)(sbase + 8192 + a1o);
            f32x4 v0 = *(const f32x4*)(sbase + 16384 + a0o);
            f32x4 v1 = *(const f32x4*)(sbase + 16384 + a1o);
            const bf16x8 AQ = cvt8h(q0, q1);
            const bf16x8 AK = cvt8h(k0, k1);
            const bf16x8 AV = cvt8h(v0, v1);
            acc[0] = MFMA(AQ, wf[s][0], acc[0]);
            acc[1] = MFMA(AK, wf[s][1], acc[1]);
            acc[2] = MFMA(AK, wf[s][2], acc[2]);
            acc[3] = MFMA(AV, wf[s][3], acc[3]);
            acc[4] = MFMA(AV, wf[s][4], acc[4]);
        }
        __syncthreads();
    }

    // --- gate epilogue: dump acc+bias to epi f32 [16][324] (reuses stage[0]) ---
    float* epi = &stage[0][0][0][0];
    #pragma unroll
    for (int j = 0; j < 5; ++j) {
        const int colj = 16 * (wid + 4 * j) + lrow;
        const float bb = b_all[colj];
        #pragma unroll
        for (int i = 0; i < 4; ++i)
            epi[(lkg * 4 + i) * 324 + colj] = acc[j][i] + bb;
    }
    __syncthreads();

    const int r = lrow;
    float p1 = 0.f, p2 = 0.f;
    #pragma unroll
    for (int jj = 0; jj < 16; ++jj) {
        const float qv = epi[r * 324 + lkg * 16 + jj];
        p1 += qv * epi[r * 324 +  64 + lkg * 16 + jj];
        p2 += qv * epi[r * 324 + 192 + lkg * 16 + jj];
    }
    p1 += __shfl_xor(p1, 16, 64); p1 += __shfl_xor(p1, 32, 64);
    p2 += __shfl_xor(p2, 16, 64); p2 += __shfl_xor(p2, 32, 64);
    const float mx = fmaxf(p1, p2);
    const float e1 = __expf(p1 - mx);
    const float e2 = __expf(p2 - mx);
    const float inv = 1.f / (e1 + e2);
    const float g1 = e1 * inv, g2 = e2 * inv;

    short* head_s = (short*)((char*)stage + 24576);   // [16][72] bf16, 2.3 KB
    const int cb = wid * 16 + lkg * 4;
    #pragma unroll
    for (int j2 = 0; j2 < 4; ++j2) {
        const float h = g1 * epi[r * 324 + 128 + cb + j2]
                      + g2 * epi[r * 324 + 256 + cb + j2];
        head_s[r * 72 + cb + j2] = f2bf_h(h);
    }
    __syncthreads();

    // --- phase 2: out[16 x 1024] = head @ W_eff^T + lh_b; wave covers 256 cols ---
    const bf16x8 ha0 = *(const bf16x8*)(head_s + lrow * 72 + lkg * 8);
    const bf16x8 ha1 = *(const bf16x8*)(head_s + lrow * 72 + 32 + lkg * 8);
    const int cgbase = wid * 256;
    #pragma unroll 2
    for (int jt = 0; jt < 16; ++jt) {
        const int col = cgbase + jt * 16 + lrow;
        const float bb = lh_b[col];
        f32x4 a = {bb, bb, bb, bb};
        const short* wp = weff + col * 64 + lkg * 8;
        a = MFMA(ha0, *(const bf16x8*)(wp), a);
        a = MFMA(ha1, *(const bf16x8*)(wp + 32), a);
        #pragma unroll
        for (int i = 0; i < 4; ++i)
            out[(size_t)(RB + lkg * 4 + i) * 1024 + col] = a[i];
    }
}

extern "C" void kernel_launch(void* const* d_in, const int* in_sizes, int n_in,
                              void* d_out, int out_size, void* d_ws, size_t ws_size,
                              hipStream_t stream) {
    const float* Q     = (const float*)d_in[0];
    const float* K     = (const float*)d_in[1];
    const float* V     = (const float*)d_in[2];
    const float* lq_w  = (const float*)d_in[3];
    const float* lq_b  = (const float*)d_in[4];
    const float* lk1_w = (const float*)d_in[5];
    const float* lk1_b = (const float*)d_in[6];
    const float* lk2_w = (const float*)d_in[7];
    const float* lk2_b = (const float*)d_in[8];
    const float* lv1_w = (const float*)d_in[9];
    const float* lv1_b = (const float*)d_in[10];
    const float* lv2_w = (const float*)d_in[11];
    const float* lv2_b = (const float*)d_in[12];
    const float* lh_w  = (const float*)d_in[13];
    const float* lh_b  = (const float*)d_in[14];
    float* out = (float*)d_out;

    short* W_all = (short*)d_ws;
    short* weff  = W_all + WS_WEFF;
    float* b_all = (float*)((char*)d_ws + WS_BALL_B);

    prep_kernel<<<1538, 256, 0, stream>>>(lq_w, lk1_w, lk2_w, lv1_w, lv2_w, lh_w,
                                          lq_b, lk1_b, lk2_b, lv1_b, lv2_b,
                                          W_all, weff, b_all);
    fused_kernel<<<2048, 256, 0, stream>>>(Q, K, V, W_all, b_all, weff, lh_b, out);
}

// Round 4
// 208.361 us; speedup vs baseline: 1.3261x; 1.0928x over previous
//
#include <hip/hip_runtime.h>
#include <hip/hip_bf16.h>

typedef __attribute__((ext_vector_type(4))) float f32x4;
typedef __attribute__((ext_vector_type(8))) short bf16x8;

#define MFMA(a, b, c) __builtin_amdgcn_mfma_f32_16x16x32_bf16(a, b, c, 0, 0, 0)

__device__ __forceinline__ short f2bf(float f) {
    union { float f; unsigned u; } v; v.f = f;
    unsigned r = v.u + 0x7fffu + ((v.u >> 16) & 1u);
    return (short)(r >> 16);
}

__device__ __forceinline__ short f2bf_h(float f) {
    __hip_bfloat16 h = __float2bfloat16(f);
    return *reinterpret_cast<const short*>(&h);
}

__device__ __forceinline__ bf16x8 cvt8h(f32x4 a, f32x4 b) {
    bf16x8 r;
    #pragma unroll
    for (int i = 0; i < 4; ++i) {
        r[i]     = f2bf_h(a[i]);
        r[4 + i] = f2bf_h(b[i]);
    }
    return r;
}

__device__ __forceinline__ void gll16(const void* g, const void* l) {
    __builtin_amdgcn_global_load_lds(
        (const __attribute__((address_space(1))) void*)g,
        (__attribute__((address_space(3))) void*)l, 16, 0, 0);
}

// ws layout:
//   W_all [320][1024] bf16 @ short 0      (rows: 0-63 q, 64-127 k1, 128-191 v1, 192-255 k2, 256-319 v2)
//   weff  [1024][64]  bf16 @ short 327680
//   b_all [320]       f32  @ byte 786432
#define WS_WEFF   327680
#define WS_BALL_B 786432

// LDS map (bytes). A buf: [3 inputs][16 rows][8 cells] of 16B (f32), 6144/buf.
// W buf: [20 tiles][16 rows][4 cells] of 16B (bf16), 20480/buf.
#define LDS_A(b)   ((b) * 6144)
#define LDS_W(b)   (12288 + (b) * 20480)
#define LDS_HEAD   22528
#define LDS_TOTAL  53248

__global__ __launch_bounds__(256) void prep_kernel(
        const float* __restrict__ lq_w, const float* __restrict__ lk1_w,
        const float* __restrict__ lk2_w, const float* __restrict__ lv1_w,
        const float* __restrict__ lv2_w, const float* __restrict__ lh_w,
        const float* __restrict__ lq_b, const float* __restrict__ lk1_b,
        const float* __restrict__ lk2_b, const float* __restrict__ lv1_b,
        const float* __restrict__ lv2_b,
        short* __restrict__ W_all, short* __restrict__ weff,
        float* __restrict__ b_all) {
    int t = blockIdx.x * 256 + threadIdx.x;
    if (t < 327680) {                       // W_all
        int row = t >> 10, col = t & 1023;
        int seg = row >> 6, sr = row & 63;
        const float* src = (seg == 0) ? lq_w : (seg == 1) ? lk1_w
                         : (seg == 2) ? lv1_w : (seg == 3) ? lk2_w : lv2_w;
        W_all[t] = f2bf(src[sr * 1024 + col]);
    } else if (t < 393216) {                // weff
        int i = t - 327680;
        int j = i >> 6, d = i & 63;
        float s = 0.f;
        #pragma unroll
        for (int h = 0; h < 16; ++h) s += lh_w[j * 1024 + h * 64 + d];
        weff[i] = f2bf(s);
    } else if (t < 393536) {                // b_all
        int i = t - 393216;
        int seg = i >> 6, si = i & 63;
        const float* src = (seg == 0) ? lq_b : (seg == 1) ? lk1_b
                         : (seg == 2) ? lv1_b : (seg == 3) ? lk2_b : lv2_b;
        b_all[i] = src[si];
    }
}

// Fused: block = 16 rows, 4 waves. K=1024 in 32 chunks of 32.
// Everything (Q/K/V f32 AND W bf16) staged via global_load_lds (cannot be
// sunk by the scheduler; zero VGPR), double-buffered; one barrier per chunk.
// Source-XOR swizzle (linear LDS dest, swizzled global src; same XOR on read).
__global__ __launch_bounds__(256, 3) void fused_kernel(
        const float* __restrict__ Q, const float* __restrict__ K,
        const float* __restrict__ V, const short* __restrict__ W_all,
        const float* __restrict__ b_all, const short* __restrict__ weff,
        const float* __restrict__ lh_b, float* __restrict__ out) {
    __shared__ __align__(16) char lds[LDS_TOTAL];
    const int tid  = threadIdx.x;
    const int wid  = tid >> 6;
    const int lane = tid & 63;
    const int lrow = lane & 15;
    const int lkg  = lane >> 4;
    const int RB   = blockIdx.x * 16;

    const float* __restrict__ Qb = Q + (size_t)RB * 1024;
    const float* __restrict__ Kb = K + (size_t)RB * 1024;
    const float* __restrict__ Vb = V + (size_t)RB * 1024;
    const float* __restrict__ Ab = (wid == 0) ? Qb : (wid == 1) ? Kb : Vb;

    // staging lane coords (fixed per thread)
    const int a_row8 = lane >> 3;          // A: row within 8-row half
    const int a_g    = lane & 7;           // A: 16B cell within row
    const int w_r4   = lane >> 2;          // W: row within 16-row tile
    const int w_q    = lane & 3;           // W: 16B cell within row

    f32x4 acc[5];
    #pragma unroll
    for (int j = 0; j < 5; ++j) acc[j] = (f32x4){0.f, 0.f, 0.f, 0.f};

    // ---- staging macro: chunk kc -> buffer b ----
    auto stage = [&](int b, int kc) {
        if (wid < 3) {
            #pragma unroll
            for (int h = 0; h < 2; ++h) {
                const int row = h * 8 + a_row8;
                const float* src = Ab + (size_t)row * 1024 + kc * 32
                                 + ((a_g ^ (row & 7)) << 2);
                gll16(src, lds + LDS_A(b) + wid * 2048 + h * 1024);
            }
        }
        #pragma unroll
        for (int j = 0; j < 5; ++j) {
            const int t = wid * 5 + j;
            const int wrow = t * 16 + w_r4;
            const short* src = W_all + (size_t)wrow * 1024 + kc * 32
                             + ((w_q ^ (wrow & 3)) << 3);
            gll16(src, lds + LDS_W(b) + t * 1024);
        }
    };

    stage(0, 0);
    __syncthreads();

    const int r7 = lrow & 7;
    const int r3 = lrow & 3;
    #pragma unroll 1
    for (int c = 0; c < 32; ++c) {
        const int cur = c & 1;
        if (c < 31) stage(cur ^ 1, c + 1);
        // compute from buf[cur]
        const char* A = lds + LDS_A(cur) + lrow * 128;
        const char* W = lds + LDS_W(cur) + lrow * 64 + ((lkg ^ r3) << 4);
        const int g0 = ((lkg * 2)     ^ r7) << 4;
        const int g1 = ((lkg * 2 + 1) ^ r7) << 4;
        f32x4 q0 = *(const f32x4*)(A + g0);
        f32x4 q1 = *(const f32x4*)(A + g1);
        f32x4 k0 = *(const f32x4*)(A + 2048 + g0);
        f32x4 k1 = *(const f32x4*)(A + 2048 + g1);
        f32x4 v0 = *(const f32x4*)(A + 4096 + g0);
        f32x4 v1 = *(const f32x4*)(A + 4096 + g1);
        bf16x8 wf0 = *(const bf16x8*)(W + (wid +  0) * 1024);
        bf16x8 wf1 = *(const bf16x8*)(W + (wid +  4) * 1024);
        bf16x8 wf2 = *(const bf16x8*)(W + (wid +  8) * 1024);
        bf16x8 wf3 = *(const bf16x8*)(W + (wid + 12) * 1024);
        bf16x8 wf4 = *(const bf16x8*)(W + (wid + 16) * 1024);
        const bf16x8 aq = cvt8h(q0, q1);
        const bf16x8 ak = cvt8h(k0, k1);
        const bf16x8 av = cvt8h(v0, v1);
        acc[0] = MFMA(aq, wf0, acc[0]);
        acc[1] = MFMA(ak, wf1, acc[1]);
        acc[2] = MFMA(ak, wf2, acc[2]);
        acc[3] = MFMA(av, wf3, acc[3]);
        acc[4] = MFMA(av, wf4, acc[4]);
        __syncthreads();
    }

    // --- gate epilogue: acc+bias -> epi f32 [16][324] (reuses staging LDS) ---
    float* epi = (float*)lds;
    #pragma unroll
    for (int j = 0; j < 5; ++j) {
        const int colj = 16 * (wid + 4 * j) + lrow;
        const float bb = b_all[colj];
        #pragma unroll
        for (int i = 0; i < 4; ++i)
            epi[(lkg * 4 + i) * 324 + colj] = acc[j][i] + bb;
    }
    __syncthreads();

    const int r = lrow;
    float p1 = 0.f, p2 = 0.f;
    #pragma unroll
    for (int jj = 0; jj < 16; ++jj) {
        const float qv = epi[r * 324 + lkg * 16 + jj];
        p1 += qv * epi[r * 324 +  64 + lkg * 16 + jj];
        p2 += qv * epi[r * 324 + 192 + lkg * 16 + jj];
    }
    p1 += __shfl_xor(p1, 16, 64); p1 += __shfl_xor(p1, 32, 64);
    p2 += __shfl_xor(p2, 16, 64); p2 += __shfl_xor(p2, 32, 64);
    const float mx = fmaxf(p1, p2);
    const float e1 = __expf(p1 - mx);
    const float e2 = __expf(p2 - mx);
    const float inv = 1.f / (e1 + e2);
    const float g1v = e1 * inv, g2v = e2 * inv;

    short* head_s = (short*)(lds + LDS_HEAD);   // [16][72] bf16
    const int cb = wid * 16 + lkg * 4;
    #pragma unroll
    for (int j2 = 0; j2 < 4; ++j2) {
        const float h = g1v * epi[r * 324 + 128 + cb + j2]
                      + g2v * epi[r * 324 + 256 + cb + j2];
        head_s[r * 72 + cb + j2] = f2bf_h(h);
    }
    __syncthreads();

    // --- phase 2: out[16 x 1024] = head @ W_eff^T + lh_b; wave = 256 cols ---
    const bf16x8 ha0 = *(const bf16x8*)(head_s + lrow * 72 + lkg * 8);
    const bf16x8 ha1 = *(const bf16x8*)(head_s + lrow * 72 + 32 + lkg * 8);
    const int cgbase = wid * 256;
    #pragma unroll 2
    for (int jt = 0; jt < 16; ++jt) {
        const int col = cgbase + jt * 16 + lrow;
        const float bb = lh_b[col];
        f32x4 a = {bb, bb, bb, bb};
        const short* wp = weff + col * 64 + lkg * 8;
        a = MFMA(ha0, *(const bf16x8*)(wp), a);
        a = MFMA(ha1, *(const bf16x8*)(wp + 32), a);
        #pragma unroll
        for (int i = 0; i < 4; ++i)
            out[(size_t)(RB + lkg * 4 + i) * 1024 + col] = a[i];
    }
}

extern "C" void kernel_launch(void* const* d_in, const int* in_sizes, int n_in,
                              void* d_out, int out_size, void* d_ws, size_t ws_size,
                              hipStream_t stream) {
    const float* Q     = (const float*)d_in[0];
    const float* K     = (const float*)d_in[1];
    const float* V     = (const float*)d_in[2];
    const float* lq_w  = (const float*)d_in[3];
    const float* lq_b  = (const float*)d_in[4];
    const float* lk1_w = (const float*)d_in[5];
    const float* lk1_b = (const float*)d_in[6];
    const float* lk2_w = (const float*)d_in[7];
    const float* lk2_b = (const float*)d_in[8];
    const float* lv1_w = (const float*)d_in[9];
    const float* lv1_b = (const float*)d_in[10];
    const float* lv2_w = (const float*)d_in[11];
    const float* lv2_b = (const float*)d_in[12];
    const float* lh_w  = (const float*)d_in[13];
    const float* lh_b  = (const float*)d_in[14];
    float* out = (float*)d_out;

    short* W_all = (short*)d_ws;
    short* weff  = W_all + WS_WEFF;
    float* b_all = (float*)((char*)d_ws + WS_BALL_B);

    prep_kernel<<<1538, 256, 0, stream>>>(lq_w, lk1_w, lk2_w, lv1_w, lv2_w, lh_w,
                                          lq_b, lk1_b, lk2_b, lv1_b, lv2_b,
                                          W_all, weff, b_all);
    fused_kernel<<<2048, 256, 0, stream>>>(Q, K, V, W_all, b_all, weff, lh_b, out);
}

// Round 5
// 163.686 us; speedup vs baseline: 1.6880x; 1.2729x over previous
//
#include <hip/hip_runtime.h>
#include <hip/hip_bf16.h>

typedef __attribute__((ext_vector_type(4))) float f32x4;
typedef __attribute__((ext_vector_type(8))) short bf16x8;

#define MFMA(a, b, c) __builtin_amdgcn_mfma_f32_16x16x32_bf16(a, b, c, 0, 0, 0)

__device__ __forceinline__ short f2bf(float f) {
    union { float f; unsigned u; } v; v.f = f;
    unsigned r = v.u + 0x7fffu + ((v.u >> 16) & 1u);
    return (short)(r >> 16);
}

__device__ __forceinline__ short f2bf_h(float f) {
    __hip_bfloat16 h = __float2bfloat16(f);
    return *reinterpret_cast<const short*>(&h);
}

__device__ __forceinline__ bf16x8 cvt8h(f32x4 a, f32x4 b) {
    bf16x8 r;
    #pragma unroll
    for (int i = 0; i < 4; ++i) {
        r[i]     = f2bf_h(a[i]);
        r[4 + i] = f2bf_h(b[i]);
    }
    return r;
}

__device__ __forceinline__ void gll16(const void* g, const void* l) {
    __builtin_amdgcn_global_load_lds(
        (const __attribute__((address_space(1))) void*)g,
        (__attribute__((address_space(3))) void*)l, 16, 0, 0);
}

// ws layout:
//   W_all [320][1024] bf16 @ short 0      (rows: seg*64+col; segs q,k1,v1,k2,v2)
//   weff  [1024][64]  bf16 @ short 327680
//   b_all [320]       f32  @ byte 786432
#define WS_WEFF   327680
#define WS_BALL_B 786432

__global__ __launch_bounds__(256) void prep_kernel(
        const float* __restrict__ lq_w, const float* __restrict__ lk1_w,
        const float* __restrict__ lk2_w, const float* __restrict__ lv1_w,
        const float* __restrict__ lv2_w, const float* __restrict__ lh_w,
        const float* __restrict__ lq_b, const float* __restrict__ lk1_b,
        const float* __restrict__ lk2_b, const float* __restrict__ lv1_b,
        const float* __restrict__ lv2_b,
        short* __restrict__ W_all, short* __restrict__ weff,
        float* __restrict__ b_all) {
    int t = blockIdx.x * 256 + threadIdx.x;
    if (t < 327680) {                       // W_all
        int row = t >> 10, col = t & 1023;
        int seg = row >> 6, sr = row & 63;
        const float* src = (seg == 0) ? lq_w : (seg == 1) ? lk1_w
                         : (seg == 2) ? lv1_w : (seg == 3) ? lk2_w : lv2_w;
        W_all[t] = f2bf(src[sr * 1024 + col]);
    } else if (t < 393216) {                // weff
        int i = t - 327680;
        int j = i >> 6, d = i & 63;
        float s = 0.f;
        #pragma unroll
        for (int h = 0; h < 16; ++h) s += lh_w[j * 1024 + h * 64 + d];
        weff[i] = f2bf(s);
    } else if (t < 393536) {                // b_all
        int i = t - 393216;
        int seg = i >> 6, si = i & 63;
        const float* src = (seg == 0) ? lq_b : (seg == 1) ? lk1_b
                         : (seg == 2) ? lv1_b : (seg == 3) ? lk2_b : lv2_b;
        b_all[i] = src[si];
    }
}

// Fused: block = 32 rows, 4 waves, K=1024 in 32 chunks of 32.
// A (Q/K/V f32): global_load_lds into 4-deep LDS ring (chunk c+3 issued at c).
// W: inline-asm global_load_dwordx4 (unsinkable) into 2 rotating reg banks.
// Counted s_waitcnt vmcnt(11) + raw s_barrier: loads stay in flight across
// barriers (T3/T4). Tail clamps kc (junk into dead buffers) to keep counts
// uniform; vmcnt(0) before the LDS epilogue reuse.
__global__ __launch_bounds__(256, 3) void fused_kernel(
        const float* __restrict__ Q, const float* __restrict__ K,
        const float* __restrict__ V, const short* __restrict__ W_all,
        const float* __restrict__ b_all, const short* __restrict__ weff,
        const float* __restrict__ lh_b, float* __restrict__ out) {
    __shared__ __align__(16) char lds[49152];   // 4 x 12KB A ring; epi reuse
    const int tid  = threadIdx.x;
    const int wid  = tid >> 6;
    const int lane = tid & 63;
    const int lrow = lane & 15;
    const int lkg  = lane >> 4;
    const int RB   = blockIdx.x * 32;

    // gll staging descriptors: 12 gll/chunk, 3 per wave (uniform for vmcnt)
    const float* asrc[3];
    int adst[3];
    #pragma unroll
    for (int u = 0; u < 3; ++u) {
        const int idx  = wid * 3 + u;         // 0..11
        const int inp  = idx >> 2;            // 0=Q 1=K 2=V
        const int rg   = idx & 3;             // 8-row group
        const int row  = rg * 8 + (lane >> 3);
        const int cell = lane & 7;            // 16B cell within 128B row-chunk
        const float* base = (inp == 0) ? Q : (inp == 1) ? K : V;
        asrc[u] = base + (size_t)(RB + row) * 1024 + ((cell ^ (row & 7)) << 2);
        adst[u] = inp * 4096 + rg * 1024;
    }

    // W fragment source pointers (L2-resident): row = seg*64 + wid*16 + lrow
    const short* wsrc[5];
    #pragma unroll
    for (int j = 0; j < 5; ++j)
        wsrc[j] = W_all + (size_t)(j * 64 + wid * 16 + lrow) * 1024 + lkg * 8;

    f32x4 acc[2][5];
    #pragma unroll
    for (int rt = 0; rt < 2; ++rt)
        #pragma unroll
        for (int j = 0; j < 5; ++j) acc[rt][j] = (f32x4){0.f, 0.f, 0.f, 0.f};

    bf16x8 wE[5], wO[5];                      // W reg banks (even/odd chunks)
    const int r7 = lrow & 7;
    const int c0 = ((lkg * 2)     ^ r7) << 4; // swizzled 16B cells on read
    const int c1 = ((lkg * 2 + 1) ^ r7) << 4;

    // ---- prologue: FIFO = A0(3), W0(5), W1(5), A1(3), A2(3) ----
    #pragma unroll
    for (int u = 0; u < 3; ++u) gll16(asrc[u], lds + adst[u]);
    #pragma unroll
    for (int j = 0; j < 5; ++j)
        asm volatile("global_load_dwordx4 %0, %1, off"
                     : "=&v"(wE[j]) : "v"(wsrc[j]) : "memory");
    #pragma unroll
    for (int j = 0; j < 5; ++j)
        asm volatile("global_load_dwordx4 %0, %1, off"
                     : "=&v"(wO[j]) : "v"(wsrc[j] + 32) : "memory");
    #pragma unroll
    for (int u = 0; u < 3; ++u) gll16(asrc[u] + 32, lds + 12288 + adst[u]);
    #pragma unroll
    for (int u = 0; u < 3; ++u) gll16(asrc[u] + 64, lds + 24576 + adst[u]);
    asm volatile("s_waitcnt vmcnt(11)" ::: "memory");  // A0,W0 done
    __builtin_amdgcn_sched_barrier(0);
    __builtin_amdgcn_s_barrier();
    __builtin_amdgcn_sched_barrier(0);

    // ---- main loop: invariant at top of iter c: A(c) in LDS, W(c) in bank ----
#define BODY(c, wb)                                                            \
    {                                                                          \
        const char* Ab = lds + ((c) & 3) * 12288;                              \
        bf16x8 fq[2], fk[2], fv[2];                                            \
        _Pragma("unroll")                                                      \
        for (int rt = 0; rt < 2; ++rt) {                                       \
            const int ro = (rt * 16 + lrow) * 128;                             \
            f32x4 q0 = *(const f32x4*)(Ab + ro + c0);                          \
            f32x4 q1 = *(const f32x4*)(Ab + ro + c1);                          \
            f32x4 k0 = *(const f32x4*)(Ab + 4096 + ro + c0);                   \
            f32x4 k1 = *(const f32x4*)(Ab + 4096 + ro + c1);                   \
            f32x4 v0 = *(const f32x4*)(Ab + 8192 + ro + c0);                   \
            f32x4 v1 = *(const f32x4*)(Ab + 8192 + ro + c1);                   \
            fq[rt] = cvt8h(q0, q1);                                            \
            fk[rt] = cvt8h(k0, k1);                                            \
            fv[rt] = cvt8h(v0, v1);                                            \
        }                                                                      \
        _Pragma("unroll")                                                      \
        for (int rt = 0; rt < 2; ++rt) {                                       \
            acc[rt][0] = MFMA(fq[rt], wb[0], acc[rt][0]);                      \
            acc[rt][1] = MFMA(fk[rt], wb[1], acc[rt][1]);                      \
            acc[rt][2] = MFMA(fk[rt], wb[2], acc[rt][2]);                      \
            acc[rt][3] = MFMA(fv[rt], wb[3], acc[rt][3]);                      \
            acc[rt][4] = MFMA(fv[rt], wb[4], acc[rt][4]);                      \
        }                                                                      \
        const int kcW = ((c) + 2 < 32) ? ((c) + 2) : 31;                       \
        _Pragma("unroll")                                                      \
        for (int j = 0; j < 5; ++j)                                            \
            asm volatile("global_load_dwordx4 %0, %1, off"                     \
                         : "=&v"(wb[j]) : "v"(wsrc[j] + kcW * 32) : "memory"); \
        const int kcA = ((c) + 3 < 32) ? ((c) + 3) : 31;                       \
        char* Db = lds + (((c) + 3) & 3) * 12288;                              \
        _Pragma("unroll")                                                      \
        for (int u = 0; u < 3; ++u)                                            \
            gll16(asrc[u] + kcA * 32, Db + adst[u]);                           \
        __builtin_amdgcn_sched_barrier(0);                                     \
        asm volatile("s_waitcnt vmcnt(11)" ::: "memory");                      \
        __builtin_amdgcn_sched_barrier(0);                                     \
        __builtin_amdgcn_s_barrier();                                          \
        __builtin_amdgcn_sched_barrier(0);                                     \
    }

    #pragma unroll 1
    for (int cc = 0; cc < 32; cc += 2) {
        BODY(cc, wE);
        BODY(cc + 1, wO);
    }
#undef BODY

    // drain everything (tail junk loads target LDS we're about to reuse)
    asm volatile("s_waitcnt vmcnt(0)" ::: "memory");
    __builtin_amdgcn_sched_barrier(0);
    __syncthreads();

    // ---- gate epilogue: acc+bias -> epi f32 [32][324] ----
    float* epi = (float*)lds;
    #pragma unroll
    for (int rt = 0; rt < 2; ++rt)
        #pragma unroll
        for (int j = 0; j < 5; ++j) {
            const int col = j * 64 + wid * 16 + lrow;
            const float bb = b_all[col];
            #pragma unroll
            for (int i = 0; i < 4; ++i)
                epi[(rt * 16 + lkg * 4 + i) * 324 + col] = acc[rt][j][i] + bb;
        }
    __syncthreads();

    // gate: row r = tid>>3, part p = tid&7 (8 lanes/row, in-wave reduce)
    const int r = tid >> 3;
    const int p = tid & 7;
    const float* er = epi + r * 324;
    float p1 = 0.f, p2 = 0.f;
    #pragma unroll
    for (int jj = 0; jj < 8; ++jj) {
        const float qv = er[p * 8 + jj];
        p1 += qv * er[64  + p * 8 + jj];    // q . k1
        p2 += qv * er[192 + p * 8 + jj];    // q . k2
    }
    p1 += __shfl_xor(p1, 1, 64); p1 += __shfl_xor(p1, 2, 64); p1 += __shfl_xor(p1, 4, 64);
    p2 += __shfl_xor(p2, 1, 64); p2 += __shfl_xor(p2, 2, 64); p2 += __shfl_xor(p2, 4, 64);
    const float mx = fmaxf(p1, p2);
    const float e1 = __expf(p1 - mx);
    const float e2 = __expf(p2 - mx);
    const float inv = 1.f / (e1 + e2);
    const float g1 = e1 * inv, g2 = e2 * inv;

    short* head_s = (short*)(lds + 41472);  // [32][72] bf16 (disjoint from epi)
    #pragma unroll
    for (int d = 0; d < 8; ++d) {
        const float h = g1 * er[128 + p * 8 + d] + g2 * er[256 + p * 8 + d];
        head_s[r * 72 + p * 8 + d] = f2bf_h(h);
    }
    __syncthreads();

    // ---- phase 2: out[32 x 1024] = head @ W_eff^T + lh_b; wave = 256 cols ----
    bf16x8 ha[2][2];
    #pragma unroll
    for (int rt = 0; rt < 2; ++rt) {
        ha[rt][0] = *(const bf16x8*)(head_s + (rt * 16 + lrow) * 72 + lkg * 8);
        ha[rt][1] = *(const bf16x8*)(head_s + (rt * 16 + lrow) * 72 + 32 + lkg * 8);
    }
    const int cgbase = wid * 256;
    #pragma unroll 4
    for (int jt = 0; jt < 16; ++jt) {
        const int col = cgbase + jt * 16 + lrow;
        const float bb = lh_b[col];
        const short* wp = weff + col * 64 + lkg * 8;
        const bf16x8 w0 = *(const bf16x8*)(wp);
        const bf16x8 w1 = *(const bf16x8*)(wp + 32);
        #pragma unroll
        for (int rt = 0; rt < 2; ++rt) {
            f32x4 a = {bb, bb, bb, bb};
            a = MFMA(ha[rt][0], w0, a);
            a = MFMA(ha[rt][1], w1, a);
            #pragma unroll
            for (int i = 0; i < 4; ++i)
                out[(size_t)(RB + rt * 16 + lkg * 4 + i) * 1024 + col] = a[i];
        }
    }
}

extern "C" void kernel_launch(void* const* d_in, const int* in_sizes, int n_in,
                              void* d_out, int out_size, void* d_ws, size_t ws_size,
                              hipStream_t stream) {
    const float* Q     = (const float*)d_in[0];
    const float* K     = (const float*)d_in[1];
    const float* V     = (const float*)d_in[2];
    const float* lq_w  = (const float*)d_in[3];
    const float* lq_b  = (const float*)d_in[4];
    const float* lk1_w = (const float*)d_in[5];
    const float* lk1_b = (const float*)d_in[6];
    const float* lk2_w = (const float*)d_in[7];
    const float* lk2_b = (const float*)d_in[8];
    const float* lv1_w = (const float*)d_in[9];
    const float* lv1_b = (const float*)d_in[10];
    const float* lv2_w = (const float*)d_in[11];
    const float* lv2_b = (const float*)d_in[12];
    const float* lh_w  = (const float*)d_in[13];
    const float* lh_b  = (const float*)d_in[14];
    float* out = (float*)d_out;

    short* W_all = (short*)d_ws;
    short* weff  = W_all + WS_WEFF;
    float* b_all = (float*)((char*)d_ws + WS_BALL_B);

    prep_kernel<<<1538, 256, 0, stream>>>(lq_w, lk1_w, lk2_w, lv1_w, lv2_w, lh_w,
                                          lq_b, lk1_b, lk2_b, lv1_b, lv2_b,
                                          W_all, weff, b_all);
    fused_kernel<<<1024, 256, 0, stream>>>(Q, K, V, W_all, b_all, weff, lh_b, out);
}